// Round 11
// baseline (659.596 us; speedup 1.0000x reference)
//
#include <hip/hip_runtime.h>

#define HW 128
#define NPIX 16384      // 128*128
#define CIN 256
#define NSC 147456      // NPIX*9
#define PRENMS 6000
#define POSTK 300
#define DW_CLIP_F 4.135166556742356f
#define MW 96           // u64 words per mask row
typedef unsigned long long ull;

// ---------------------------------------------------------------- weight transpose + scratch zero
// w: [co=256][k=2304] -> wt: [k=2304][co=256]; also zeroes hist1+hist2+meta
// (contiguous, 82 KB) and validbits.
__global__ void wt_kernel(const float* __restrict__ w, float* __restrict__ wt,
                          unsigned* __restrict__ zp, ull* __restrict__ vb) {
    int i = blockIdx.x * 256 + threadIdx.x;
    if (i < 2304 * 256) {
        int k = i >> 8, co = i & 255;
        wt[i] = w[co * 2304 + k];
    }
    if (i < 16384 + 65536 + 64) zp[i] = 0u;
    if (i < 94) vb[i] = 0ull;
}

// ---------------------------------------------------------------- 3x3 conv, K-split halves
// EXACT R1 structure (best measured: 240us, VALUBusy ~62%, conflicts 0, bit-exact).
__global__ __launch_bounds__(256) void conv3x3_half_kernel(
    const float* __restrict__ feat, const float* __restrict__ wt,
    float* __restrict__ part)
{
    __shared__ float in_s[16 * 340];    // 16 ci * (10 rows * 34 floats) = 21760 B
    const int tx = threadIdx.x;         // 0..31
    const int ty = threadIdx.y;         // 0..7
    const int x0 = blockIdx.x * 32;
    const int y0 = blockIdx.y * 8;
    const int h  = blockIdx.z >> 3;
    const int co0 = (blockIdx.z & 7) << 5;
    const int tid = ty * 32 + tx;

    // staging geometry computed ONCE (patch 10 x 34 = 340 entries, 256 threads)
    const int yy1 = tid / 34, xx1 = tid - yy1 * 34;
    const int t2 = tid + 256;
    const int yy2 = t2 / 34, xx2 = t2 - yy2 * 34;
    const int gy1 = y0 + yy1 - 1, gx1 = x0 + xx1 - 1;
    const int gy2 = y0 + yy2 - 1, gx2 = x0 + xx2 - 1;
    const bool p1 = ((unsigned)gy1 < 128u) && ((unsigned)gx1 < 128u);
    const bool p2 = (tid < 84) && ((unsigned)gy2 < 128u) && ((unsigned)gx2 < 128u);
    const int a1 = p1 ? (gy1 * 128 + gx1) : 0;
    const int a2 = p2 ? (gy2 * 128 + gx2) : 0;

    float acc[32];
#pragma unroll
    for (int i = 0; i < 32; ++i) acc[i] = 0.f;

    const float* fh = feat + h * 128 * NPIX;
    const float* wh = wt + h * 128 * 9 * 256;

    for (int s = 0; s < 8; ++s) {
        __syncthreads();
        const float* fbase = fh + s * 16 * NPIX;
#pragma unroll
        for (int ci = 0; ci < 16; ++ci) {
            float t = fbase[ci * NPIX + a1];
            in_s[ci * 340 + tid] = p1 ? t : 0.f;
        }
        if (tid < 84) {
#pragma unroll
            for (int ci = 0; ci < 16; ++ci) {
                float t = fbase[ci * NPIX + a2];
                in_s[ci * 340 + 256 + tid] = p2 ? t : 0.f;
            }
        }
        __syncthreads();
        const float* ws0 = wh + s * 16 * 9 * 256 + co0;
#pragma unroll 2
        for (int ci = 0; ci < 16; ++ci) {
            const float* wrow = ws0 + ci * 9 * 256;
#pragma unroll
            for (int t = 0; t < 9; ++t) {
                const int ky = t / 3, kx = t - ky * 3;
                float v = in_s[ci * 340 + (ty + ky) * 34 + (tx + kx)];
                const float* wp = wrow + t * 256;   // wave-uniform -> s_load_dwordx16
#pragma unroll
                for (int co = 0; co < 32; ++co)
                    acc[co] = fmaf(v, wp[co], acc[co]);
            }
        }
    }
    float* po = part + h * (CIN * NPIX) + co0 * NPIX + (y0 + ty) * 128 + (x0 + tx);
#pragma unroll
    for (int co = 0; co < 32; ++co)
        po[co * NPIX] = acc[co];
}

// ---------------------------------------------------------------- 1x1 heads (+ fused combine)
__global__ __launch_bounds__(256) void heads_kernel(
    const float* __restrict__ part, const float* __restrict__ conv_b,
    const float* __restrict__ cls_w, const float* __restrict__ cls_b,
    const float* __restrict__ bbox_w, const float* __restrict__ bbox_b,
    float* __restrict__ scores, float* __restrict__ bb)
{
    __shared__ float wl[256][48];   // [ci][slot], 0-8 = cls, 9-44 = bbox, 45-47 = 0
    const int tid = threadIdx.x;
    for (int e = tid; e < 256 * 48; e += 256) {
        int ci = e / 48, s = e - ci * 48;
        wl[ci][s] = (s < 9) ? cls_w[s * CIN + ci]
                  : (s < 45) ? bbox_w[(s - 9) * CIN + ci] : 0.f;
    }
    __syncthreads();

    const int lane = tid & 63;
    const int sg   = tid >> 6;          // slot group 0..3
    const int p    = blockIdx.x * 64 + lane;
    const int s0   = sg * 12;
    const int ns   = (sg == 3) ? 9 : 12;

    float acc[12];
#pragma unroll
    for (int i = 0; i < 12; ++i) acc[i] = 0.f;

    const float* part1 = part + CIN * NPIX;
#pragma unroll 4
    for (int ci = 0; ci < CIN; ++ci) {
        float a = part[ci * NPIX + p];
        float c = part1[ci * NPIX + p];
        float v = fmaxf(a + c + conv_b[ci], 0.f);   // verbatim combine expr
        const float* wr = &wl[ci][s0];
#pragma unroll
        for (int j = 0; j < 12; ++j)
            acc[j] = fmaf(v, wr[j], acc[j]);
    }
    for (int j = 0; j < ns; ++j) {
        int s = s0 + j;
        if (s < 9) {
            float sc = acc[j] + cls_b[s];
            scores[p * 9 + s] = 1.0f / (1.0f + expf(-sc));
        } else {
            bb[(s - 9) * NPIX + p] = acc[j] + bbox_b[s - 9];
        }
    }
}

// ---------------------------------------------------------------- coarse histogram (64 blocks, LDS-privatized)
__global__ __launch_bounds__(1024) void hist1_kernel(const float* __restrict__ scores,
                                                     unsigned* __restrict__ hist1) {
    __shared__ unsigned h[16384];
    const int tid = threadIdx.x;
    for (int i = tid; i < 16384; i += 1024) h[i] = 0u;
    __syncthreads();
    for (int i = blockIdx.x * 1024 + tid; i < NSC; i += gridDim.x * 1024) {
        unsigned bits = __float_as_uint(scores[i]);
        atomicAdd(&h[bits >> 16], 1u);
    }
    __syncthreads();
    for (int i = tid; i < 16384; i += 1024) {
        unsigned c = h[i];
        if (c) atomicAdd(&hist1[i], c);
    }
}

// ---------------------------------------------------------------- fused scan1 + fine-threshold + compact (single block)
__global__ __launch_bounds__(1024) void topk_finish_kernel(
    const float* __restrict__ scores, const unsigned* __restrict__ hist1,
    unsigned* __restrict__ meta, ull* __restrict__ cand)
{
    __shared__ unsigned sh[1024];
    __shared__ unsigned g2[256];
    __shared__ unsigned res[8];     // [0]=m1 [1]=cAbove [2]=g* [3]=need3 [4]=b* [5]=pos
    const int tid = threadIdx.x;

    // ---- scan1 (verbatim R7 body; ssum->sh, meta writes->res)
    {
        unsigned local[16];
        unsigned s = 0;
#pragma unroll
        for (int i = 0; i < 16; ++i) { local[i] = hist1[tid * 16 + i]; s += local[i]; }
        sh[tid] = s;
        __syncthreads();
        for (int off = 1; off < 1024; off <<= 1) {
            unsigned v = sh[tid] + ((tid + off < 1024) ? sh[tid + off] : 0u);
            __syncthreads();
            sh[tid] = v;
            __syncthreads();
        }
        unsigned run = sh[tid] - s;
#pragma unroll
        for (int i = 15; i >= 0; --i) {
            unsigned nb = run + local[i];
            if (nb >= (unsigned)PRENMS && run < (unsigned)PRENMS) {
                res[0] = (unsigned)(tid * 16 + i);
                res[1] = run;
            }
            run = nb;
        }
    }
    __syncthreads();
    const unsigned m1 = res[0];
    const unsigned need2 = (unsigned)PRENMS - res[1];
    const uint4* s4 = (const uint4*)scores;   // NSC/4 = 36864, 16B-aligned

    // ---- pass A: group histogram (bucket m1, groups = bits[15:8])
    if (tid < 256) g2[tid] = 0u;
    __syncthreads();
    for (int i = tid; i < NSC / 4; i += 1024) {
        uint4 v = s4[i];
        if ((v.x >> 16) == m1) atomicAdd(&g2[(v.x >> 8) & 0xFF], 1u);
        if ((v.y >> 16) == m1) atomicAdd(&g2[(v.y >> 8) & 0xFF], 1u);
        if ((v.z >> 16) == m1) atomicAdd(&g2[(v.z >> 8) & 0xFF], 1u);
        if ((v.w >> 16) == m1) atomicAdd(&g2[(v.w >> 8) & 0xFF], 1u);
    }
    __syncthreads();
    {
        unsigned hg = (tid < 256) ? g2[tid] : 0u;
        __syncthreads();
        for (int off = 1; off < 256; off <<= 1) {
            unsigned v = 0;
            if (tid < 256) v = g2[tid] + ((tid + off < 256) ? g2[tid + off] : 0u);
            __syncthreads();
            if (tid < 256) g2[tid] = v;
            __syncthreads();
        }
        if (tid < 256) {
            unsigned above = g2[tid] - hg;          // count in groups > tid
            if (above < need2 && above + hg >= need2) {
                res[2] = (unsigned)tid;
                res[3] = need2 - above;
            }
        }
    }
    __syncthreads();
    const unsigned gstar = res[2];
    const unsigned need3 = res[3];
    const unsigned pref = (m1 << 8) | gstar;        // bits>>8 == pref

    // ---- pass B: sub-bin histogram within (m1, g*), bins = bits[7:0]
    if (tid < 256) g2[tid] = 0u;
    __syncthreads();
    for (int i = tid; i < NSC / 4; i += 1024) {
        uint4 v = s4[i];
        if ((v.x >> 8) == pref) atomicAdd(&g2[v.x & 0xFF], 1u);
        if ((v.y >> 8) == pref) atomicAdd(&g2[v.y & 0xFF], 1u);
        if ((v.z >> 8) == pref) atomicAdd(&g2[v.z & 0xFF], 1u);
        if ((v.w >> 8) == pref) atomicAdd(&g2[v.w & 0xFF], 1u);
    }
    __syncthreads();
    {
        unsigned hb = (tid < 256) ? g2[tid] : 0u;
        __syncthreads();
        for (int off = 1; off < 256; off <<= 1) {
            unsigned v = 0;
            if (tid < 256) v = g2[tid] + ((tid + off < 256) ? g2[tid + off] : 0u);
            __syncthreads();
            if (tid < 256) g2[tid] = v;
            __syncthreads();
        }
        if (tid < 256) {
            unsigned above = g2[tid] - hb;
            if (above < need3 && above + hb >= need3) res[4] = (unsigned)tid;
        }
    }
    __syncthreads();
    const unsigned thr = (m1 << 16) | (gstar << 8) | res[4];

    // ---- pass C: compact (wave-ballot, LDS position counter)
    if (tid == 0) res[5] = 0u;
    __syncthreads();
    const int lane = tid & 63;
    for (int i = tid; i < NSC / 4; i += 1024) {
        uint4 v = s4[i];
        unsigned b[4] = { v.x, v.y, v.z, v.w };
#pragma unroll
        for (int k = 0; k < 4; ++k) {
            bool pred = b[k] >= thr;
            ull bal = __ballot(pred);
            unsigned cnt = (unsigned)__popcll(bal);
            unsigned base = 0;
            if (lane == 0 && cnt) base = atomicAdd(&res[5], cnt);
            base = __shfl(base, 0);
            if (pred) {
                unsigned off = (unsigned)__popcll(bal & ((1ull << lane) - 1ull));
                unsigned pos = base + off;
                int gi = i * 4 + k;
                if (pos < 8192u)
                    cand[pos] = ((ull)b[k] << 32) | (unsigned)(~gi);
            }
        }
    }
    __syncthreads();
    if (tid == 0) meta[0] = res[5];
}

// ---------------------------------------------------------------- full bitonic sort (8192 in LDS) + fused decode
// Replaces sortA (4 blocks) + merge_decode (2 dispatches -> 1). Single block,
// keys[8192] = 64KB LDS (same static size R6's select_kernel used). Comparator
// network is old sortA's extended to k=8192 -> full descending sort; keys unique
// -> order identical to old 4-sort + rank-merge. After sort, keys[r] IS rank r;
// decode formulas verbatim. Threshold construction guarantees >=6000 real keys
// (real keys >= 2^32 > padding 8191-i), so ranks < PRENMS are always real.
__global__ __launch_bounds__(1024) void sort_decode_kernel(
    const ull* __restrict__ cand, const unsigned* __restrict__ meta,
    const float* __restrict__ bb,
    float* __restrict__ selbox, float* __restrict__ selsc,
    ull* __restrict__ validbits)
{
    __shared__ ull keys[8192];      // 65536 B
    const int tid = threadIdx.x;
    const int n = min((int)meta[0], 8192);
    for (int i = tid; i < 8192; i += 1024)
        keys[i] = (i < n) ? cand[i] : (ull)(8191 - i);
    __syncthreads();
    for (int k = 2; k <= 8192; k <<= 1) {
        for (int j = k >> 1; j >= 1; j >>= 1) {
            for (int s = tid; s < 4096; s += 1024) {
                int i = ((s & ~(j - 1)) << 1) | (s & (j - 1));
                int p = i | j;
                ull a = keys[i], c = keys[p];
                bool desc = ((i & k) == 0);
                bool sw = desc ? (a < c) : (a > c);
                if (sw) { keys[i] = c; keys[p] = a; }
            }
            __syncthreads();
        }
    }
    for (int r = tid; r < PRENMS; r += 1024) {
        ull x = keys[r];
        unsigned sbits = (unsigned)(x >> 32);
        unsigned idx = ~(unsigned)(x & 0xFFFFFFFFull);
        float score = __uint_as_float(sbits);
        int p = (int)(idx / 9u);
        int a = (int)(idx - (unsigned)p * 9u);
        int y = p >> 7, xx = p & 127;
        float d0 = bb[(a * 4 + 0) * NPIX + p];
        float d1 = bb[(a * 4 + 1) * NPIX + p];
        float d2 = bb[(a * 4 + 2) * NPIX + p];
        float d3 = bb[(a * 4 + 3) * NPIX + p];
        int ar_i = a / 3, sc_i = a - ar_i * 3;
        float arv = (ar_i == 0) ? 0.5f : ((ar_i == 1) ? 1.0f : 2.0f);
        float scv = (sc_i == 0) ? 128.f : ((sc_i == 1) ? 256.f : 512.f);
        float hr = sqrtf(arv);
        float wr = 1.0f / hr;
        float hs = hr * scv;
        float wsv = wr * scv;
        float bx1 = rintf(-wsv * 0.5f), by1 = rintf(-hs * 0.5f);
        float bx2 = rintf(wsv * 0.5f),  by2 = rintf(hs * 0.5f);
        float ax1 = xx * 8.f + bx1, ay1 = y * 8.f + by1;
        float ax2 = xx * 8.f + bx2, ay2 = y * 8.f + by2;
        float wa = ax2 - ax1, ha = ay2 - ay1;
        float cx = ax1 + 0.5f * wa, cy = ay1 + 0.5f * ha;
        float dw = fminf(d2, DW_CLIP_F), dh = fminf(d3, DW_CLIP_F);
        float px = d0 * wa + cx, py = d1 * ha + cy;
        float pw = expf(dw) * wa, ph = expf(dh) * ha;
        float x1 = px - 0.5f * pw, y1 = py - 0.5f * ph;
        float x2 = px + 0.5f * pw, y2 = py + 0.5f * ph;
        x1 = fminf(fmaxf(x1, 0.f), 1024.f);
        y1 = fminf(fmaxf(y1, 0.f), 1024.f);
        x2 = fminf(fmaxf(x2, 0.f), 1024.f);
        y2 = fminf(fmaxf(y2, 0.f), 1024.f);
        float bw = x2 - x1, bh = y2 - y1;
        bool valid = (bw >= 16.f) && (bh >= 16.f);
        selbox[r * 4 + 0] = x1; selbox[r * 4 + 1] = y1;
        selbox[r * 4 + 2] = x2; selbox[r * 4 + 3] = y2;
        selsc[r] = score;
        if (valid) atomicOr(&validbits[r >> 6], 1ull << (r & 63));
    }
}

// ---------------------------------------------------------------- IOU suppression mask build
__global__ __launch_bounds__(256) void maskbuild_kernel(
    const float* __restrict__ selbox, ull* __restrict__ mask)
{
    __shared__ float jb0[64], jb1[64], jb2[64], jb3[64];
    const int jw = blockIdx.y;
    const int tid = threadIdx.x;
    const int i = blockIdx.x * 256 + tid;
    if (jw * 64 + 63 < blockIdx.x * 256) {
        if (i < PRENMS) mask[(size_t)i * MW + jw] = 0ull;
        return;
    }
    if (tid < 64) {
        int j = jw * 64 + tid;
        float x1 = 0.f, y1 = 0.f, x2 = 0.f, y2 = 0.f;
        if (j < PRENMS) {
            x1 = selbox[j * 4 + 0]; y1 = selbox[j * 4 + 1];
            x2 = selbox[j * 4 + 2]; y2 = selbox[j * 4 + 3];
        }
        jb0[tid] = x1; jb1[tid] = y1; jb2[tid] = x2; jb3[tid] = y2;
    }
    __syncthreads();
    if (i >= PRENMS) return;
    const float ix1 = selbox[i * 4 + 0], iy1 = selbox[i * 4 + 1];
    const float ix2 = selbox[i * 4 + 2], iy2 = selbox[i * 4 + 3];
    const float iarea = (ix2 - ix1) * (iy2 - iy1);
    ull word = 0ull;
    for (int b = 0; b < 64; ++b) {
        int j = jw * 64 + b;
        float xx1 = fmaxf(ix1, jb0[b]);
        float yy1 = fmaxf(iy1, jb1[b]);
        float xx2 = fminf(ix2, jb2[b]);
        float yy2 = fminf(iy2, jb3[b]);
        float iw = fmaxf(xx2 - xx1, 0.f);
        float ih = fmaxf(yy2 - yy1, 0.f);
        float inter = iw * ih;
        float jarea = (jb2[b] - jb0[b]) * (jb3[b] - jb1[b]);
        float iou = inter / (iarea + jarea - inter);
        if (j > i && iou > 0.7f) word |= (1ull << b);
    }
    mask[(size_t)i * MW + jw] = word;
}

// ---------------------------------------------------------------- chunked single-wave greedy NMS
__global__ __launch_bounds__(64) void nms_scan_kernel(
    const ull* __restrict__ validbits,
    const ull* __restrict__ mask,
    const float* __restrict__ selbox, const float* __restrict__ selsc,
    float* __restrict__ out)
{
    __shared__ int kept[POSTK];
    const int l = threadIdx.x;
    ull supp0 = ~validbits[l];
    ull supp1 = (l < 30) ? ~validbits[64 + l] : ~0ull;
    int nk = 0;
    ull ownrow_next = mask[(size_t)l * MW + 0];
    for (int wi = 0; wi < 94 && nk < POSTK; ++wi) {
        ull ownrow = ownrow_next;
        if (wi < 93) ownrow_next = mask[(size_t)((wi + 1) * 64 + l) * MW + (wi + 1)];
        ull wsup = (wi < 64) ? __shfl(supp0, wi) : __shfl(supp1, wi - 64);
        ull active = ~wsup;
        if (!active) continue;
        ull keptbits = 0ull;
        while (active && nk < POSTK) {
            int b = __builtin_ctzll(active);
            keptbits |= (1ull << b);
            if (l == 0) kept[nk] = wi * 64 + b;
            nk++;
            ull rowb = __shfl(ownrow, b);
            ull gt = (b == 63) ? 0ull : (~0ull << (b + 1));
            active &= gt & ~rowb;
        }
        while (keptbits) {
            int b0 = __builtin_ctzll(keptbits); keptbits &= keptbits - 1;
            int b1 = -1, b2 = -1, b3 = -1;
            if (keptbits) { b1 = __builtin_ctzll(keptbits); keptbits &= keptbits - 1; }
            if (keptbits) { b2 = __builtin_ctzll(keptbits); keptbits &= keptbits - 1; }
            if (keptbits) { b3 = __builtin_ctzll(keptbits); keptbits &= keptbits - 1; }
            const ull* r0 = mask + (size_t)(wi * 64 + b0) * MW;
            ull t0a = r0[l], t0b = (l < 30) ? r0[64 + l] : 0ull;
            ull t1a = 0, t1b = 0, t2a = 0, t2b = 0, t3a = 0, t3b = 0;
            if (b1 >= 0) { const ull* r1 = mask + (size_t)(wi * 64 + b1) * MW; t1a = r1[l]; t1b = (l < 30) ? r1[64 + l] : 0ull; }
            if (b2 >= 0) { const ull* r2 = mask + (size_t)(wi * 64 + b2) * MW; t2a = r2[l]; t2b = (l < 30) ? r2[64 + l] : 0ull; }
            if (b3 >= 0) { const ull* r3 = mask + (size_t)(wi * 64 + b3) * MW; t3a = r3[l]; t3b = (l < 30) ? r3[64 + l] : 0ull; }
            supp0 |= t0a | t1a | t2a | t3a;
            supp1 |= t0b | t1b | t2b | t3b;
        }
    }
    __syncthreads();
    for (int r = l; r < POSTK; r += 64) {
        if (r < nk) {
            int i = kept[r];
            out[r * 5 + 0] = selbox[i * 4 + 0];
            out[r * 5 + 1] = selbox[i * 4 + 1];
            out[r * 5 + 2] = selbox[i * 4 + 2];
            out[r * 5 + 3] = selbox[i * 4 + 3];
            out[r * 5 + 4] = selsc[i];
        } else {
            out[r * 5 + 0] = 0.f; out[r * 5 + 1] = 0.f;
            out[r * 5 + 2] = 0.f; out[r * 5 + 3] = 0.f;
            out[r * 5 + 4] = 0.f;
        }
    }
}

// ---------------------------------------------------------------- launch
extern "C" void kernel_launch(void* const* d_in, const int* in_sizes, int n_in,
                              void* d_out, int out_size, void* d_ws, size_t ws_size,
                              hipStream_t stream) {
    const float* feat    = (const float*)d_in[1];
    const float* conv_w  = (const float*)d_in[2];
    const float* conv_b  = (const float*)d_in[3];
    const float* cls_w   = (const float*)d_in[4];
    const float* cls_b   = (const float*)d_in[5];
    const float* bbox_w  = (const float*)d_in[6];
    const float* bbox_b  = (const float*)d_in[7];
    float* out = (float*)d_out;

    char* ws = (char*)d_ws;
    float*    part      = (float*)(ws + 0);                 // 33,554,432 (2 halves)
    float*    wt        = (float*)(ws + 33554432);          //  2,359,296
    float*    bb        = (float*)(ws + 35913728);          //  2,359,296
    float*    scores    = (float*)(ws + 38273024);          //    589,824
    unsigned* hist1     = (unsigned*)(ws + 38862848);       //     65,536
    unsigned* meta      = (unsigned*)(ws + 39190528);       //        256
    ull*      cand      = (ull*)(ws + 39190784);            //     65,536
    float*    selbox    = (float*)(ws + 39387392);          //     96,256
    float*    selsc     = (float*)(ws + 39483648);          //     24,064
    ull*      validbits = (ull*)(ws + 39507712);            //        768
    ull*      mask      = (ull*)(ws + 39508480);            //  4,608,000  -> total 44,116,480

    wt_kernel<<<2304, 256, 0, stream>>>(conv_w, wt, hist1, validbits);
    conv3x3_half_kernel<<<dim3(4, 16, 16), dim3(32, 8), 0, stream>>>(feat, wt, part);
    heads_kernel<<<256, 256, 0, stream>>>(part, conv_b, cls_w, cls_b, bbox_w, bbox_b, scores, bb);
    hist1_kernel<<<64, 1024, 0, stream>>>(scores, hist1);
    topk_finish_kernel<<<1, 1024, 0, stream>>>(scores, hist1, meta, cand);
    sort_decode_kernel<<<1, 1024, 0, stream>>>(cand, meta, bb, selbox, selsc, validbits);
    maskbuild_kernel<<<dim3(24, 94), 256, 0, stream>>>(selbox, mask);
    nms_scan_kernel<<<1, 64, 0, stream>>>(validbits, mask, selbox, selsc, out);
}

// Round 12
// 537.880 us; speedup vs baseline: 1.2263x; 1.2263x over previous
//
#include <hip/hip_runtime.h>

#define HW 128
#define NPIX 16384      // 128*128
#define CIN 256
#define NSC 147456      // NPIX*9
#define PRENMS 6000
#define POSTK 300
#define DW_CLIP_F 4.135166556742356f
#define MW 96           // u64 words per mask row
typedef unsigned long long ull;

// ---------------------------------------------------------------- weight transpose + scratch zero
// w: [co=256][k=2304] -> wt: [k=2304][co=256]; also zeroes hist1+hist2+meta
// (contiguous, 82 KB) and validbits.
__global__ void wt_kernel(const float* __restrict__ w, float* __restrict__ wt,
                          unsigned* __restrict__ zp, ull* __restrict__ vb) {
    int i = blockIdx.x * 256 + threadIdx.x;
    if (i < 2304 * 256) {
        int k = i >> 8, co = i & 255;
        wt[i] = w[co * 2304 + k];
    }
    if (i < 16384 + 65536 + 64) zp[i] = 0u;
    if (i < 94) vb[i] = 0ull;
}

// ---------------------------------------------------------------- 3x3 conv, K-split halves
// R12: 64x8 spatial tile (512 thr, 8 waves), co=32, ci-chunk 16 -> 512 blocks,
// 2/CU, 16 waves/CU (same as R1's 4x256). Rationale: idle ~90-110us was invariant
// to conflicts/barriers/prefetch and WORSE at 8 blocks/CU (R3) -> per-CU scalar
// K$ fill bandwidth for weights is the stall (72KB/CU/s-iter through 16KB K$).
// Doubling spatial tile halves weight traffic per FLOP (36KB/CU/s-iter).
// Row stride 66 (wave = one 64-wide row -> 2 lanes/bank, conflict-free).
// Summation order per output (s -> ci -> tap) identical -> bit-exact.
__global__ __launch_bounds__(512) void conv3x3_half_kernel(
    const float* __restrict__ feat, const float* __restrict__ wt,
    float* __restrict__ part)
{
    __shared__ float in_s[16 * 660];    // 16 ci * (10 rows * 66 floats) = 42,240 B
    const int tx = threadIdx.x;         // 0..63
    const int ty = threadIdx.y;         // 0..7
    const int x0 = blockIdx.x * 64;
    const int y0 = blockIdx.y * 8;
    const int h  = blockIdx.z >> 3;
    const int co0 = (blockIdx.z & 7) << 5;
    const int tid = ty * 64 + tx;       // 0..511

    // staging geometry computed ONCE (patch 10 x 66 = 660 entries, 512 threads)
    const int yy1 = tid / 66, xx1 = tid - yy1 * 66;
    const int t2 = tid + 512;
    const int yy2 = t2 / 66, xx2 = t2 - yy2 * 66;
    const int gy1 = y0 + yy1 - 1, gx1 = x0 + xx1 - 1;
    const int gy2 = y0 + yy2 - 1, gx2 = x0 + xx2 - 1;
    const bool p1 = ((unsigned)gy1 < 128u) && ((unsigned)gx1 < 128u);
    const bool p2 = (tid < 148) && ((unsigned)gy2 < 128u) && ((unsigned)gx2 < 128u);
    const int a1 = p1 ? (gy1 * 128 + gx1) : 0;
    const int a2 = p2 ? (gy2 * 128 + gx2) : 0;

    float acc[32];
#pragma unroll
    for (int i = 0; i < 32; ++i) acc[i] = 0.f;

    const float* fh = feat + h * 128 * NPIX;
    const float* wh = wt + h * 128 * 9 * 256;

    for (int s = 0; s < 8; ++s) {
        __syncthreads();
        const float* fbase = fh + s * 16 * NPIX;
#pragma unroll
        for (int ci = 0; ci < 16; ++ci) {
            float t = fbase[ci * NPIX + a1];
            in_s[ci * 660 + tid] = p1 ? t : 0.f;
        }
        if (tid < 148) {
#pragma unroll
            for (int ci = 0; ci < 16; ++ci) {
                float t = fbase[ci * NPIX + a2];
                in_s[ci * 660 + 512 + tid] = p2 ? t : 0.f;
            }
        }
        __syncthreads();
        const float* ws0 = wh + s * 16 * 9 * 256 + co0;
#pragma unroll 2
        for (int ci = 0; ci < 16; ++ci) {
            const float* wrow = ws0 + ci * 9 * 256;
#pragma unroll
            for (int t = 0; t < 9; ++t) {
                const int ky = t / 3, kx = t - ky * 3;
                float v = in_s[ci * 660 + (ty + ky) * 66 + (tx + kx)];
                const float* wp = wrow + t * 256;   // wave-uniform -> s_load_dwordx16
#pragma unroll
                for (int co = 0; co < 32; ++co)
                    acc[co] = fmaf(v, wp[co], acc[co]);
            }
        }
    }
    float* po = part + h * (CIN * NPIX) + co0 * NPIX + (y0 + ty) * 128 + (x0 + tx);
#pragma unroll
    for (int co = 0; co < 32; ++co)
        po[co * NPIX] = acc[co];
}

// ---------------------------------------------------------------- 1x1 heads (+ fused combine)
__global__ __launch_bounds__(256) void heads_kernel(
    const float* __restrict__ part, const float* __restrict__ conv_b,
    const float* __restrict__ cls_w, const float* __restrict__ cls_b,
    const float* __restrict__ bbox_w, const float* __restrict__ bbox_b,
    float* __restrict__ scores, float* __restrict__ bb)
{
    __shared__ float wl[256][48];   // [ci][slot], 0-8 = cls, 9-44 = bbox, 45-47 = 0
    const int tid = threadIdx.x;
    for (int e = tid; e < 256 * 48; e += 256) {
        int ci = e / 48, s = e - ci * 48;
        wl[ci][s] = (s < 9) ? cls_w[s * CIN + ci]
                  : (s < 45) ? bbox_w[(s - 9) * CIN + ci] : 0.f;
    }
    __syncthreads();

    const int lane = tid & 63;
    const int sg   = tid >> 6;          // slot group 0..3
    const int p    = blockIdx.x * 64 + lane;
    const int s0   = sg * 12;
    const int ns   = (sg == 3) ? 9 : 12;

    float acc[12];
#pragma unroll
    for (int i = 0; i < 12; ++i) acc[i] = 0.f;

    const float* part1 = part + CIN * NPIX;
#pragma unroll 4
    for (int ci = 0; ci < CIN; ++ci) {
        float a = part[ci * NPIX + p];
        float c = part1[ci * NPIX + p];
        float v = fmaxf(a + c + conv_b[ci], 0.f);   // verbatim combine expr
        const float* wr = &wl[ci][s0];
#pragma unroll
        for (int j = 0; j < 12; ++j)
            acc[j] = fmaf(v, wr[j], acc[j]);
    }
    for (int j = 0; j < ns; ++j) {
        int s = s0 + j;
        if (s < 9) {
            float sc = acc[j] + cls_b[s];
            scores[p * 9 + s] = 1.0f / (1.0f + expf(-sc));
        } else {
            bb[(s - 9) * NPIX + p] = acc[j] + bbox_b[s - 9];
        }
    }
}

// ---------------------------------------------------------------- coarse histogram (64 blocks, LDS-privatized)
__global__ __launch_bounds__(1024) void hist1_kernel(const float* __restrict__ scores,
                                                     unsigned* __restrict__ hist1) {
    __shared__ unsigned h[16384];
    const int tid = threadIdx.x;
    for (int i = tid; i < 16384; i += 1024) h[i] = 0u;
    __syncthreads();
    for (int i = blockIdx.x * 1024 + tid; i < NSC; i += gridDim.x * 1024) {
        unsigned bits = __float_as_uint(scores[i]);
        atomicAdd(&h[bits >> 16], 1u);
    }
    __syncthreads();
    for (int i = tid; i < 16384; i += 1024) {
        unsigned c = h[i];
        if (c) atomicAdd(&hist1[i], c);
    }
}

// ---------------------------------------------------------------- fused scan1 + fine-threshold + compact (single block)
__global__ __launch_bounds__(1024) void topk_finish_kernel(
    const float* __restrict__ scores, const unsigned* __restrict__ hist1,
    unsigned* __restrict__ meta, ull* __restrict__ cand)
{
    __shared__ unsigned sh[1024];
    __shared__ unsigned g2[256];
    __shared__ unsigned res[8];     // [0]=m1 [1]=cAbove [2]=g* [3]=need3 [4]=b* [5]=pos
    const int tid = threadIdx.x;

    // ---- scan1 (verbatim R7 body; ssum->sh, meta writes->res)
    {
        unsigned local[16];
        unsigned s = 0;
#pragma unroll
        for (int i = 0; i < 16; ++i) { local[i] = hist1[tid * 16 + i]; s += local[i]; }
        sh[tid] = s;
        __syncthreads();
        for (int off = 1; off < 1024; off <<= 1) {
            unsigned v = sh[tid] + ((tid + off < 1024) ? sh[tid + off] : 0u);
            __syncthreads();
            sh[tid] = v;
            __syncthreads();
        }
        unsigned run = sh[tid] - s;
#pragma unroll
        for (int i = 15; i >= 0; --i) {
            unsigned nb = run + local[i];
            if (nb >= (unsigned)PRENMS && run < (unsigned)PRENMS) {
                res[0] = (unsigned)(tid * 16 + i);
                res[1] = run;
            }
            run = nb;
        }
    }
    __syncthreads();
    const unsigned m1 = res[0];
    const unsigned need2 = (unsigned)PRENMS - res[1];
    const uint4* s4 = (const uint4*)scores;   // NSC/4 = 36864, 16B-aligned

    // ---- pass A: group histogram (bucket m1, groups = bits[15:8])
    if (tid < 256) g2[tid] = 0u;
    __syncthreads();
    for (int i = tid; i < NSC / 4; i += 1024) {
        uint4 v = s4[i];
        if ((v.x >> 16) == m1) atomicAdd(&g2[(v.x >> 8) & 0xFF], 1u);
        if ((v.y >> 16) == m1) atomicAdd(&g2[(v.y >> 8) & 0xFF], 1u);
        if ((v.z >> 16) == m1) atomicAdd(&g2[(v.z >> 8) & 0xFF], 1u);
        if ((v.w >> 16) == m1) atomicAdd(&g2[(v.w >> 8) & 0xFF], 1u);
    }
    __syncthreads();
    {
        unsigned hg = (tid < 256) ? g2[tid] : 0u;
        __syncthreads();
        for (int off = 1; off < 256; off <<= 1) {
            unsigned v = 0;
            if (tid < 256) v = g2[tid] + ((tid + off < 256) ? g2[tid + off] : 0u);
            __syncthreads();
            if (tid < 256) g2[tid] = v;
            __syncthreads();
        }
        if (tid < 256) {
            unsigned above = g2[tid] - hg;          // count in groups > tid
            if (above < need2 && above + hg >= need2) {
                res[2] = (unsigned)tid;
                res[3] = need2 - above;
            }
        }
    }
    __syncthreads();
    const unsigned gstar = res[2];
    const unsigned need3 = res[3];
    const unsigned pref = (m1 << 8) | gstar;        // bits>>8 == pref

    // ---- pass B: sub-bin histogram within (m1, g*), bins = bits[7:0]
    if (tid < 256) g2[tid] = 0u;
    __syncthreads();
    for (int i = tid; i < NSC / 4; i += 1024) {
        uint4 v = s4[i];
        if ((v.x >> 8) == pref) atomicAdd(&g2[v.x & 0xFF], 1u);
        if ((v.y >> 8) == pref) atomicAdd(&g2[v.y & 0xFF], 1u);
        if ((v.z >> 8) == pref) atomicAdd(&g2[v.z & 0xFF], 1u);
        if ((v.w >> 8) == pref) atomicAdd(&g2[v.w & 0xFF], 1u);
    }
    __syncthreads();
    {
        unsigned hb = (tid < 256) ? g2[tid] : 0u;
        __syncthreads();
        for (int off = 1; off < 256; off <<= 1) {
            unsigned v = 0;
            if (tid < 256) v = g2[tid] + ((tid + off < 256) ? g2[tid + off] : 0u);
            __syncthreads();
            if (tid < 256) g2[tid] = v;
            __syncthreads();
        }
        if (tid < 256) {
            unsigned above = g2[tid] - hb;
            if (above < need3 && above + hb >= need3) res[4] = (unsigned)tid;
        }
    }
    __syncthreads();
    const unsigned thr = (m1 << 16) | (gstar << 8) | res[4];

    // ---- pass C: compact (wave-ballot, LDS position counter)
    if (tid == 0) res[5] = 0u;
    __syncthreads();
    const int lane = tid & 63;
    for (int i = tid; i < NSC / 4; i += 1024) {
        uint4 v = s4[i];
        unsigned b[4] = { v.x, v.y, v.z, v.w };
#pragma unroll
        for (int k = 0; k < 4; ++k) {
            bool pred = b[k] >= thr;
            ull bal = __ballot(pred);
            unsigned cnt = (unsigned)__popcll(bal);
            unsigned base = 0;
            if (lane == 0 && cnt) base = atomicAdd(&res[5], cnt);
            base = __shfl(base, 0);
            if (pred) {
                unsigned off = (unsigned)__popcll(bal & ((1ull << lane) - 1ull));
                unsigned pos = base + off;
                int gi = i * 4 + k;
                if (pos < 8192u)
                    cand[pos] = ((ull)b[k] << 32) | (unsigned)(~gi);
            }
        }
    }
    __syncthreads();
    if (tid == 0) meta[0] = res[5];
}

// ---------------------------------------------------------------- parallel sort: 4 local sorts
__global__ __launch_bounds__(1024) void sortA_kernel(const ull* __restrict__ cand,
                                                     const unsigned* __restrict__ meta,
                                                     ull* __restrict__ sorted) {
    __shared__ ull keys[2048];
    const int tid = threadIdx.x;
    const int base = blockIdx.x * 2048;
    const int n = min((int)meta[0], 8192);
    for (int i = tid; i < 2048; i += 1024) {
        int g = base + i;
        keys[i] = (g < n) ? cand[g] : (ull)(8191 - g);
    }
    __syncthreads();
    for (int k = 2; k <= 2048; k <<= 1) {
        for (int j = k >> 1; j >= 1; j >>= 1) {
            int s = tid;
            int i = ((s & ~(j - 1)) << 1) | (s & (j - 1));
            int p = i | j;
            ull a = keys[i], c = keys[p];
            bool desc = ((i & k) == 0);
            bool sw = desc ? (a < c) : (a > c);
            if (sw) { keys[i] = c; keys[p] = a; }
            __syncthreads();
        }
    }
    for (int i = tid; i < 2048; i += 1024) sorted[base + i] = keys[i];
}

// ---------------------------------------------------------------- rank-merge + fused decode
__global__ __launch_bounds__(256) void merge_decode_kernel(
    const ull* __restrict__ sorted, const float* __restrict__ bb,
    float* __restrict__ selbox, float* __restrict__ selsc,
    ull* __restrict__ validbits)
{
    const int g = blockIdx.x * 256 + threadIdx.x;   // 32 blocks -> 8192
    ull x = sorted[g];
    const int c = g >> 11;
    int rank = g & 2047;
#pragma unroll
    for (int cc = 0; cc < 4; ++cc) {
        if (cc == c) continue;
        const ull* arr = sorted + cc * 2048;
        int lo = 0, hi = 2048;
        while (lo < hi) { int mid = (lo + hi) >> 1; if (arr[mid] > x) lo = mid + 1; else hi = mid; }
        rank += lo;
    }
    if (rank < PRENMS) {
        const int r = rank;
        unsigned sbits = (unsigned)(x >> 32);
        unsigned idx = ~(unsigned)(x & 0xFFFFFFFFull);
        float score = __uint_as_float(sbits);
        int p = (int)(idx / 9u);
        int a = (int)(idx - (unsigned)p * 9u);
        int y = p >> 7, xx = p & 127;
        float d0 = bb[(a * 4 + 0) * NPIX + p];
        float d1 = bb[(a * 4 + 1) * NPIX + p];
        float d2 = bb[(a * 4 + 2) * NPIX + p];
        float d3 = bb[(a * 4 + 3) * NPIX + p];
        int ar_i = a / 3, sc_i = a - ar_i * 3;
        float arv = (ar_i == 0) ? 0.5f : ((ar_i == 1) ? 1.0f : 2.0f);
        float scv = (sc_i == 0) ? 128.f : ((sc_i == 1) ? 256.f : 512.f);
        float hr = sqrtf(arv);
        float wr = 1.0f / hr;
        float hs = hr * scv;
        float wsv = wr * scv;
        float bx1 = rintf(-wsv * 0.5f), by1 = rintf(-hs * 0.5f);
        float bx2 = rintf(wsv * 0.5f),  by2 = rintf(hs * 0.5f);
        float ax1 = xx * 8.f + bx1, ay1 = y * 8.f + by1;
        float ax2 = xx * 8.f + bx2, ay2 = y * 8.f + by2;
        float wa = ax2 - ax1, ha = ay2 - ay1;
        float cx = ax1 + 0.5f * wa, cy = ay1 + 0.5f * ha;
        float dw = fminf(d2, DW_CLIP_F), dh = fminf(d3, DW_CLIP_F);
        float px = d0 * wa + cx, py = d1 * ha + cy;
        float pw = expf(dw) * wa, ph = expf(dh) * ha;
        float x1 = px - 0.5f * pw, y1 = py - 0.5f * ph;
        float x2 = px + 0.5f * pw, y2 = py + 0.5f * ph;
        x1 = fminf(fmaxf(x1, 0.f), 1024.f);
        y1 = fminf(fmaxf(y1, 0.f), 1024.f);
        x2 = fminf(fmaxf(x2, 0.f), 1024.f);
        y2 = fminf(fmaxf(y2, 0.f), 1024.f);
        float bw = x2 - x1, bh = y2 - y1;
        bool valid = (bw >= 16.f) && (bh >= 16.f);
        selbox[r * 4 + 0] = x1; selbox[r * 4 + 1] = y1;
        selbox[r * 4 + 2] = x2; selbox[r * 4 + 3] = y2;
        selsc[r] = score;
        if (valid) atomicOr(&validbits[r >> 6], 1ull << (r & 63));
    }
}

// ---------------------------------------------------------------- IOU suppression mask build
__global__ __launch_bounds__(256) void maskbuild_kernel(
    const float* __restrict__ selbox, ull* __restrict__ mask)
{
    __shared__ float jb0[64], jb1[64], jb2[64], jb3[64];
    const int jw = blockIdx.y;
    const int tid = threadIdx.x;
    const int i = blockIdx.x * 256 + tid;
    if (jw * 64 + 63 < blockIdx.x * 256) {
        if (i < PRENMS) mask[(size_t)i * MW + jw] = 0ull;
        return;
    }
    if (tid < 64) {
        int j = jw * 64 + tid;
        float x1 = 0.f, y1 = 0.f, x2 = 0.f, y2 = 0.f;
        if (j < PRENMS) {
            x1 = selbox[j * 4 + 0]; y1 = selbox[j * 4 + 1];
            x2 = selbox[j * 4 + 2]; y2 = selbox[j * 4 + 3];
        }
        jb0[tid] = x1; jb1[tid] = y1; jb2[tid] = x2; jb3[tid] = y2;
    }
    __syncthreads();
    if (i >= PRENMS) return;
    const float ix1 = selbox[i * 4 + 0], iy1 = selbox[i * 4 + 1];
    const float ix2 = selbox[i * 4 + 2], iy2 = selbox[i * 4 + 3];
    const float iarea = (ix2 - ix1) * (iy2 - iy1);
    ull word = 0ull;
    for (int b = 0; b < 64; ++b) {
        int j = jw * 64 + b;
        float xx1 = fmaxf(ix1, jb0[b]);
        float yy1 = fmaxf(iy1, jb1[b]);
        float xx2 = fminf(ix2, jb2[b]);
        float yy2 = fminf(iy2, jb3[b]);
        float iw = fmaxf(xx2 - xx1, 0.f);
        float ih = fmaxf(yy2 - yy1, 0.f);
        float inter = iw * ih;
        float jarea = (jb2[b] - jb0[b]) * (jb3[b] - jb1[b]);
        float iou = inter / (iarea + jarea - inter);
        if (j > i && iou > 0.7f) word |= (1ull << b);
    }
    mask[(size_t)i * MW + jw] = word;
}

// ---------------------------------------------------------------- chunked single-wave greedy NMS
__global__ __launch_bounds__(64) void nms_scan_kernel(
    const ull* __restrict__ validbits,
    const ull* __restrict__ mask,
    const float* __restrict__ selbox, const float* __restrict__ selsc,
    float* __restrict__ out)
{
    __shared__ int kept[POSTK];
    const int l = threadIdx.x;
    ull supp0 = ~validbits[l];
    ull supp1 = (l < 30) ? ~validbits[64 + l] : ~0ull;
    int nk = 0;
    ull ownrow_next = mask[(size_t)l * MW + 0];
    for (int wi = 0; wi < 94 && nk < POSTK; ++wi) {
        ull ownrow = ownrow_next;
        if (wi < 93) ownrow_next = mask[(size_t)((wi + 1) * 64 + l) * MW + (wi + 1)];
        ull wsup = (wi < 64) ? __shfl(supp0, wi) : __shfl(supp1, wi - 64);
        ull active = ~wsup;
        if (!active) continue;
        ull keptbits = 0ull;
        while (active && nk < POSTK) {
            int b = __builtin_ctzll(active);
            keptbits |= (1ull << b);
            if (l == 0) kept[nk] = wi * 64 + b;
            nk++;
            ull rowb = __shfl(ownrow, b);
            ull gt = (b == 63) ? 0ull : (~0ull << (b + 1));
            active &= gt & ~rowb;
        }
        while (keptbits) {
            int b0 = __builtin_ctzll(keptbits); keptbits &= keptbits - 1;
            int b1 = -1, b2 = -1, b3 = -1;
            if (keptbits) { b1 = __builtin_ctzll(keptbits); keptbits &= keptbits - 1; }
            if (keptbits) { b2 = __builtin_ctzll(keptbits); keptbits &= keptbits - 1; }
            if (keptbits) { b3 = __builtin_ctzll(keptbits); keptbits &= keptbits - 1; }
            const ull* r0 = mask + (size_t)(wi * 64 + b0) * MW;
            ull t0a = r0[l], t0b = (l < 30) ? r0[64 + l] : 0ull;
            ull t1a = 0, t1b = 0, t2a = 0, t2b = 0, t3a = 0, t3b = 0;
            if (b1 >= 0) { const ull* r1 = mask + (size_t)(wi * 64 + b1) * MW; t1a = r1[l]; t1b = (l < 30) ? r1[64 + l] : 0ull; }
            if (b2 >= 0) { const ull* r2 = mask + (size_t)(wi * 64 + b2) * MW; t2a = r2[l]; t2b = (l < 30) ? r2[64 + l] : 0ull; }
            if (b3 >= 0) { const ull* r3 = mask + (size_t)(wi * 64 + b3) * MW; t3a = r3[l]; t3b = (l < 30) ? r3[64 + l] : 0ull; }
            supp0 |= t0a | t1a | t2a | t3a;
            supp1 |= t0b | t1b | t2b | t3b;
        }
    }
    __syncthreads();
    for (int r = l; r < POSTK; r += 64) {
        if (r < nk) {
            int i = kept[r];
            out[r * 5 + 0] = selbox[i * 4 + 0];
            out[r * 5 + 1] = selbox[i * 4 + 1];
            out[r * 5 + 2] = selbox[i * 4 + 2];
            out[r * 5 + 3] = selbox[i * 4 + 3];
            out[r * 5 + 4] = selsc[i];
        } else {
            out[r * 5 + 0] = 0.f; out[r * 5 + 1] = 0.f;
            out[r * 5 + 2] = 0.f; out[r * 5 + 3] = 0.f;
            out[r * 5 + 4] = 0.f;
        }
    }
}

// ---------------------------------------------------------------- launch
extern "C" void kernel_launch(void* const* d_in, const int* in_sizes, int n_in,
                              void* d_out, int out_size, void* d_ws, size_t ws_size,
                              hipStream_t stream) {
    const float* feat    = (const float*)d_in[1];
    const float* conv_w  = (const float*)d_in[2];
    const float* conv_b  = (const float*)d_in[3];
    const float* cls_w   = (const float*)d_in[4];
    const float* cls_b   = (const float*)d_in[5];
    const float* bbox_w  = (const float*)d_in[6];
    const float* bbox_b  = (const float*)d_in[7];
    float* out = (float*)d_out;

    char* ws = (char*)d_ws;
    float*    part      = (float*)(ws + 0);                 // 33,554,432 (2 halves)
    float*    wt        = (float*)(ws + 33554432);          //  2,359,296
    float*    bb        = (float*)(ws + 35913728);          //  2,359,296
    float*    scores    = (float*)(ws + 38273024);          //    589,824
    unsigned* hist1     = (unsigned*)(ws + 38862848);       //     65,536
    unsigned* meta      = (unsigned*)(ws + 39190528);       //        256
    ull*      cand      = (ull*)(ws + 39190784);            //     65,536
    ull*      sorted    = (ull*)(ws + 39256320);            //     65,536
    float*    selbox    = (float*)(ws + 39387392);          //     96,256
    float*    selsc     = (float*)(ws + 39483648);          //     24,064
    ull*      validbits = (ull*)(ws + 39507712);            //        768
    ull*      mask      = (ull*)(ws + 39508480);            //  4,608,000  -> total 44,116,480

    wt_kernel<<<2304, 256, 0, stream>>>(conv_w, wt, hist1, validbits);
    conv3x3_half_kernel<<<dim3(2, 16, 16), dim3(64, 8), 0, stream>>>(feat, wt, part);
    heads_kernel<<<256, 256, 0, stream>>>(part, conv_b, cls_w, cls_b, bbox_w, bbox_b, scores, bb);
    hist1_kernel<<<64, 1024, 0, stream>>>(scores, hist1);
    topk_finish_kernel<<<1, 1024, 0, stream>>>(scores, hist1, meta, cand);
    sortA_kernel<<<4, 1024, 0, stream>>>(cand, meta, sorted);
    merge_decode_kernel<<<32, 256, 0, stream>>>(sorted, bb, selbox, selsc, validbits);
    maskbuild_kernel<<<dim3(24, 94), 256, 0, stream>>>(selbox, mask);
    nms_scan_kernel<<<1, 64, 0, stream>>>(validbits, mask, selbox, selsc, out);
}

// Round 14
// 518.996 us; speedup vs baseline: 1.2709x; 1.0364x over previous
//
#include <hip/hip_runtime.h>

#define HW 128
#define NPIX 16384      // 128*128
#define CIN 256
#define NSC 147456      // NPIX*9
#define PRENMS 6000
#define POSTK 300
#define DW_CLIP_F 4.135166556742356f
#define MW 96           // u64 words per mask row
typedef unsigned long long ull;

// ---------------------------------------------------------------- weight transpose + scratch zero
// w: [co=256][k=2304] -> wt: [k=2304][co=256]; also zeroes hist1+hist2+meta
// (contiguous, 82 KB) and validbits.
__global__ void wt_kernel(const float* __restrict__ w, float* __restrict__ wt,
                          unsigned* __restrict__ zp, ull* __restrict__ vb) {
    int i = blockIdx.x * 256 + threadIdx.x;
    if (i < 2304 * 256) {
        int k = i >> 8, co = i & 255;
        wt[i] = w[co * 2304 + k];
    }
    if (i < 16384 + 65536 + 64) zp[i] = 0u;
    if (i < 94) vb[i] = 0ull;
}

// ---------------------------------------------------------------- 3x3 conv, K-split halves
// EXACT R1 structure -- the empirical optimum of 7 explored conv variants
// (240us, VALUBusy ~62%, conflicts 0, bit-exact; ~78% of the MEASURED 103 TF
// fp32 VALU ceiling = 188us FMA floor). fp32 is mandatory (no fp32 MFMA on
// CDNA4; bit-exact top-k boundary forbids precision change).
__global__ __launch_bounds__(256) void conv3x3_half_kernel(
    const float* __restrict__ feat, const float* __restrict__ wt,
    float* __restrict__ part)
{
    __shared__ float in_s[16 * 340];    // 16 ci * (10 rows * 34 floats) = 21760 B
    const int tx = threadIdx.x;         // 0..31
    const int ty = threadIdx.y;         // 0..7
    const int x0 = blockIdx.x * 32;
    const int y0 = blockIdx.y * 8;
    const int h  = blockIdx.z >> 3;
    const int co0 = (blockIdx.z & 7) << 5;
    const int tid = ty * 32 + tx;

    // staging geometry computed ONCE (patch 10 x 34 = 340 entries, 256 threads)
    const int yy1 = tid / 34, xx1 = tid - yy1 * 34;
    const int t2 = tid + 256;
    const int yy2 = t2 / 34, xx2 = t2 - yy2 * 34;
    const int gy1 = y0 + yy1 - 1, gx1 = x0 + xx1 - 1;
    const int gy2 = y0 + yy2 - 1, gx2 = x0 + xx2 - 1;
    const bool p1 = ((unsigned)gy1 < 128u) && ((unsigned)gx1 < 128u);
    const bool p2 = (tid < 84) && ((unsigned)gy2 < 128u) && ((unsigned)gx2 < 128u);
    const int a1 = p1 ? (gy1 * 128 + gx1) : 0;
    const int a2 = p2 ? (gy2 * 128 + gx2) : 0;

    float acc[32];
#pragma unroll
    for (int i = 0; i < 32; ++i) acc[i] = 0.f;

    const float* fh = feat + h * 128 * NPIX;
    const float* wh = wt + h * 128 * 9 * 256;

    for (int s = 0; s < 8; ++s) {
        __syncthreads();
        const float* fbase = fh + s * 16 * NPIX;
#pragma unroll
        for (int ci = 0; ci < 16; ++ci) {
            float t = fbase[ci * NPIX + a1];
            in_s[ci * 340 + tid] = p1 ? t : 0.f;
        }
        if (tid < 84) {
#pragma unroll
            for (int ci = 0; ci < 16; ++ci) {
                float t = fbase[ci * NPIX + a2];
                in_s[ci * 340 + 256 + tid] = p2 ? t : 0.f;
            }
        }
        __syncthreads();
        const float* ws0 = wh + s * 16 * 9 * 256 + co0;
#pragma unroll 2
        for (int ci = 0; ci < 16; ++ci) {
            const float* wrow = ws0 + ci * 9 * 256;
#pragma unroll
            for (int t = 0; t < 9; ++t) {
                const int ky = t / 3, kx = t - ky * 3;
                float v = in_s[ci * 340 + (ty + ky) * 34 + (tx + kx)];
                const float* wp = wrow + t * 256;   // wave-uniform -> s_load_dwordx16
#pragma unroll
                for (int co = 0; co < 32; ++co)
                    acc[co] = fmaf(v, wp[co], acc[co]);
            }
        }
    }
    float* po = part + h * (CIN * NPIX) + co0 * NPIX + (y0 + ty) * 128 + (x0 + tx);
#pragma unroll
    for (int co = 0; co < 32; ++co)
        po[co * NPIX] = acc[co];
}

// ---------------------------------------------------------------- 1x1 heads (+ fused combine)
__global__ __launch_bounds__(256) void heads_kernel(
    const float* __restrict__ part, const float* __restrict__ conv_b,
    const float* __restrict__ cls_w, const float* __restrict__ cls_b,
    const float* __restrict__ bbox_w, const float* __restrict__ bbox_b,
    float* __restrict__ scores, float* __restrict__ bb)
{
    __shared__ float wl[256][48];   // [ci][slot], 0-8 = cls, 9-44 = bbox, 45-47 = 0
    const int tid = threadIdx.x;
    for (int e = tid; e < 256 * 48; e += 256) {
        int ci = e / 48, s = e - ci * 48;
        wl[ci][s] = (s < 9) ? cls_w[s * CIN + ci]
                  : (s < 45) ? bbox_w[(s - 9) * CIN + ci] : 0.f;
    }
    __syncthreads();

    const int lane = tid & 63;
    const int sg   = tid >> 6;          // slot group 0..3
    const int p    = blockIdx.x * 64 + lane;
    const int s0   = sg * 12;
    const int ns   = (sg == 3) ? 9 : 12;

    float acc[12];
#pragma unroll
    for (int i = 0; i < 12; ++i) acc[i] = 0.f;

    const float* part1 = part + CIN * NPIX;
#pragma unroll 4
    for (int ci = 0; ci < CIN; ++ci) {
        float a = part[ci * NPIX + p];
        float c = part1[ci * NPIX + p];
        float v = fmaxf(a + c + conv_b[ci], 0.f);   // verbatim combine expr
        const float* wr = &wl[ci][s0];
#pragma unroll
        for (int j = 0; j < 12; ++j)
            acc[j] = fmaf(v, wr[j], acc[j]);
    }
    for (int j = 0; j < ns; ++j) {
        int s = s0 + j;
        if (s < 9) {
            float sc = acc[j] + cls_b[s];
            scores[p * 9 + s] = 1.0f / (1.0f + expf(-sc));
        } else {
            bb[(s - 9) * NPIX + p] = acc[j] + bbox_b[s - 9];
        }
    }
}

// ---------------------------------------------------------------- coarse histogram (64 blocks, LDS-privatized)
__global__ __launch_bounds__(1024) void hist1_kernel(const float* __restrict__ scores,
                                                     unsigned* __restrict__ hist1) {
    __shared__ unsigned h[16384];
    const int tid = threadIdx.x;
    for (int i = tid; i < 16384; i += 1024) h[i] = 0u;
    __syncthreads();
    for (int i = blockIdx.x * 1024 + tid; i < NSC; i += gridDim.x * 1024) {
        unsigned bits = __float_as_uint(scores[i]);
        atomicAdd(&h[bits >> 16], 1u);
    }
    __syncthreads();
    for (int i = tid; i < 16384; i += 1024) {
        unsigned c = h[i];
        if (c) atomicAdd(&hist1[i], c);
    }
}

// ---------------------------------------------------------------- fused scan1 + fine-threshold + compact (single block)
__global__ __launch_bounds__(1024) void topk_finish_kernel(
    const float* __restrict__ scores, const unsigned* __restrict__ hist1,
    unsigned* __restrict__ meta, ull* __restrict__ cand)
{
    __shared__ unsigned sh[1024];
    __shared__ unsigned g2[256];
    __shared__ unsigned res[8];     // [0]=m1 [1]=cAbove [2]=g* [3]=need3 [4]=b* [5]=pos
    const int tid = threadIdx.x;

    // ---- scan1 (verbatim R7 body; ssum->sh, meta writes->res)
    {
        unsigned local[16];
        unsigned s = 0;
#pragma unroll
        for (int i = 0; i < 16; ++i) { local[i] = hist1[tid * 16 + i]; s += local[i]; }
        sh[tid] = s;
        __syncthreads();
        for (int off = 1; off < 1024; off <<= 1) {
            unsigned v = sh[tid] + ((tid + off < 1024) ? sh[tid + off] : 0u);
            __syncthreads();
            sh[tid] = v;
            __syncthreads();
        }
        unsigned run = sh[tid] - s;
#pragma unroll
        for (int i = 15; i >= 0; --i) {
            unsigned nb = run + local[i];
            if (nb >= (unsigned)PRENMS && run < (unsigned)PRENMS) {
                res[0] = (unsigned)(tid * 16 + i);
                res[1] = run;
            }
            run = nb;
        }
    }
    __syncthreads();
    const unsigned m1 = res[0];
    const unsigned need2 = (unsigned)PRENMS - res[1];
    const uint4* s4 = (const uint4*)scores;   // NSC/4 = 36864, 16B-aligned

    // ---- pass A: group histogram (bucket m1, groups = bits[15:8])
    if (tid < 256) g2[tid] = 0u;
    __syncthreads();
    for (int i = tid; i < NSC / 4; i += 1024) {
        uint4 v = s4[i];
        if ((v.x >> 16) == m1) atomicAdd(&g2[(v.x >> 8) & 0xFF], 1u);
        if ((v.y >> 16) == m1) atomicAdd(&g2[(v.y >> 8) & 0xFF], 1u);
        if ((v.z >> 16) == m1) atomicAdd(&g2[(v.z >> 8) & 0xFF], 1u);
        if ((v.w >> 16) == m1) atomicAdd(&g2[(v.w >> 8) & 0xFF], 1u);
    }
    __syncthreads();
    {
        unsigned hg = (tid < 256) ? g2[tid] : 0u;
        __syncthreads();
        for (int off = 1; off < 256; off <<= 1) {
            unsigned v = 0;
            if (tid < 256) v = g2[tid] + ((tid + off < 256) ? g2[tid + off] : 0u);
            __syncthreads();
            if (tid < 256) g2[tid] = v;
            __syncthreads();
        }
        if (tid < 256) {
            unsigned above = g2[tid] - hg;          // count in groups > tid
            if (above < need2 && above + hg >= need2) {
                res[2] = (unsigned)tid;
                res[3] = need2 - above;
            }
        }
    }
    __syncthreads();
    const unsigned gstar = res[2];
    const unsigned need3 = res[3];
    const unsigned pref = (m1 << 8) | gstar;        // bits>>8 == pref

    // ---- pass B: sub-bin histogram within (m1, g*), bins = bits[7:0]
    if (tid < 256) g2[tid] = 0u;
    __syncthreads();
    for (int i = tid; i < NSC / 4; i += 1024) {
        uint4 v = s4[i];
        if ((v.x >> 8) == pref) atomicAdd(&g2[v.x & 0xFF], 1u);
        if ((v.y >> 8) == pref) atomicAdd(&g2[v.y & 0xFF], 1u);
        if ((v.z >> 8) == pref) atomicAdd(&g2[v.z & 0xFF], 1u);
        if ((v.w >> 8) == pref) atomicAdd(&g2[v.w & 0xFF], 1u);
    }
    __syncthreads();
    {
        unsigned hb = (tid < 256) ? g2[tid] : 0u;
        __syncthreads();
        for (int off = 1; off < 256; off <<= 1) {
            unsigned v = 0;
            if (tid < 256) v = g2[tid] + ((tid + off < 256) ? g2[tid + off] : 0u);
            __syncthreads();
            if (tid < 256) g2[tid] = v;
            __syncthreads();
        }
        if (tid < 256) {
            unsigned above = g2[tid] - hb;
            if (above < need3 && above + hb >= need3) res[4] = (unsigned)tid;
        }
    }
    __syncthreads();
    const unsigned thr = (m1 << 16) | (gstar << 8) | res[4];

    // ---- pass C: compact (wave-ballot, LDS position counter)
    if (tid == 0) res[5] = 0u;
    __syncthreads();
    const int lane = tid & 63;
    for (int i = tid; i < NSC / 4; i += 1024) {
        uint4 v = s4[i];
        unsigned b[4] = { v.x, v.y, v.z, v.w };
#pragma unroll
        for (int k = 0; k < 4; ++k) {
            bool pred = b[k] >= thr;
            ull bal = __ballot(pred);
            unsigned cnt = (unsigned)__popcll(bal);
            unsigned base = 0;
            if (lane == 0 && cnt) base = atomicAdd(&res[5], cnt);
            base = __shfl(base, 0);
            if (pred) {
                unsigned off = (unsigned)__popcll(bal & ((1ull << lane) - 1ull));
                unsigned pos = base + off;
                int gi = i * 4 + k;
                if (pos < 8192u)
                    cand[pos] = ((ull)b[k] << 32) | (unsigned)(~gi);
            }
        }
    }
    __syncthreads();
    if (tid == 0) meta[0] = res[5];
}

// ---------------------------------------------------------------- parallel sort: 4 local sorts
__global__ __launch_bounds__(1024) void sortA_kernel(const ull* __restrict__ cand,
                                                     const unsigned* __restrict__ meta,
                                                     ull* __restrict__ sorted) {
    __shared__ ull keys[2048];
    const int tid = threadIdx.x;
    const int base = blockIdx.x * 2048;
    const int n = min((int)meta[0], 8192);
    for (int i = tid; i < 2048; i += 1024) {
        int g = base + i;
        keys[i] = (g < n) ? cand[g] : (ull)(8191 - g);
    }
    __syncthreads();
    for (int k = 2; k <= 2048; k <<= 1) {
        for (int j = k >> 1; j >= 1; j >>= 1) {
            int s = tid;
            int i = ((s & ~(j - 1)) << 1) | (s & (j - 1));
            int p = i | j;
            ull a = keys[i], c = keys[p];
            bool desc = ((i & k) == 0);
            bool sw = desc ? (a < c) : (a > c);
            if (sw) { keys[i] = c; keys[p] = a; }
            __syncthreads();
        }
    }
    for (int i = tid; i < 2048; i += 1024) sorted[base + i] = keys[i];
}

// ---------------------------------------------------------------- rank-merge + fused decode
__global__ __launch_bounds__(256) void merge_decode_kernel(
    const ull* __restrict__ sorted, const float* __restrict__ bb,
    float* __restrict__ selbox, float* __restrict__ selsc,
    ull* __restrict__ validbits)
{
    const int g = blockIdx.x * 256 + threadIdx.x;   // 32 blocks -> 8192
    ull x = sorted[g];
    const int c = g >> 11;
    int rank = g & 2047;
#pragma unroll
    for (int cc = 0; cc < 4; ++cc) {
        if (cc == c) continue;
        const ull* arr = sorted + cc * 2048;
        int lo = 0, hi = 2048;
        while (lo < hi) { int mid = (lo + hi) >> 1; if (arr[mid] > x) lo = mid + 1; else hi = mid; }
        rank += lo;
    }
    if (rank < PRENMS) {
        const int r = rank;
        unsigned sbits = (unsigned)(x >> 32);
        unsigned idx = ~(unsigned)(x & 0xFFFFFFFFull);
        float score = __uint_as_float(sbits);
        int p = (int)(idx / 9u);
        int a = (int)(idx - (unsigned)p * 9u);
        int y = p >> 7, xx = p & 127;
        float d0 = bb[(a * 4 + 0) * NPIX + p];
        float d1 = bb[(a * 4 + 1) * NPIX + p];
        float d2 = bb[(a * 4 + 2) * NPIX + p];
        float d3 = bb[(a * 4 + 3) * NPIX + p];
        int ar_i = a / 3, sc_i = a - ar_i * 3;
        float arv = (ar_i == 0) ? 0.5f : ((ar_i == 1) ? 1.0f : 2.0f);
        float scv = (sc_i == 0) ? 128.f : ((sc_i == 1) ? 256.f : 512.f);
        float hr = sqrtf(arv);
        float wr = 1.0f / hr;
        float hs = hr * scv;
        float wsv = wr * scv;
        float bx1 = rintf(-wsv * 0.5f), by1 = rintf(-hs * 0.5f);
        float bx2 = rintf(wsv * 0.5f),  by2 = rintf(hs * 0.5f);
        float ax1 = xx * 8.f + bx1, ay1 = y * 8.f + by1;
        float ax2 = xx * 8.f + bx2, ay2 = y * 8.f + by2;
        float wa = ax2 - ax1, ha = ay2 - ay1;
        float cx = ax1 + 0.5f * wa, cy = ay1 + 0.5f * ha;
        float dw = fminf(d2, DW_CLIP_F), dh = fminf(d3, DW_CLIP_F);
        float px = d0 * wa + cx, py = d1 * ha + cy;
        float pw = expf(dw) * wa, ph = expf(dh) * ha;
        float x1 = px - 0.5f * pw, y1 = py - 0.5f * ph;
        float x2 = px + 0.5f * pw, y2 = py + 0.5f * ph;
        x1 = fminf(fmaxf(x1, 0.f), 1024.f);
        y1 = fminf(fmaxf(y1, 0.f), 1024.f);
        x2 = fminf(fmaxf(x2, 0.f), 1024.f);
        y2 = fminf(fmaxf(y2, 0.f), 1024.f);
        float bw = x2 - x1, bh = y2 - y1;
        bool valid = (bw >= 16.f) && (bh >= 16.f);
        selbox[r * 4 + 0] = x1; selbox[r * 4 + 1] = y1;
        selbox[r * 4 + 2] = x2; selbox[r * 4 + 3] = y2;
        selsc[r] = score;
        if (valid) atomicOr(&validbits[r >> 6], 1ull << (r & 63));
    }
}

// ---------------------------------------------------------------- IOU suppression mask build
__global__ __launch_bounds__(256) void maskbuild_kernel(
    const float* __restrict__ selbox, ull* __restrict__ mask)
{
    __shared__ float jb0[64], jb1[64], jb2[64], jb3[64];
    const int jw = blockIdx.y;
    const int tid = threadIdx.x;
    const int i = blockIdx.x * 256 + tid;
    if (jw * 64 + 63 < blockIdx.x * 256) {
        if (i < PRENMS) mask[(size_t)i * MW + jw] = 0ull;
        return;
    }
    if (tid < 64) {
        int j = jw * 64 + tid;
        float x1 = 0.f, y1 = 0.f, x2 = 0.f, y2 = 0.f;
        if (j < PRENMS) {
            x1 = selbox[j * 4 + 0]; y1 = selbox[j * 4 + 1];
            x2 = selbox[j * 4 + 2]; y2 = selbox[j * 4 + 3];
        }
        jb0[tid] = x1; jb1[tid] = y1; jb2[tid] = x2; jb3[tid] = y2;
    }
    __syncthreads();
    if (i >= PRENMS) return;
    const float ix1 = selbox[i * 4 + 0], iy1 = selbox[i * 4 + 1];
    const float ix2 = selbox[i * 4 + 2], iy2 = selbox[i * 4 + 3];
    const float iarea = (ix2 - ix1) * (iy2 - iy1);
    ull word = 0ull;
    for (int b = 0; b < 64; ++b) {
        int j = jw * 64 + b;
        float xx1 = fmaxf(ix1, jb0[b]);
        float yy1 = fmaxf(iy1, jb1[b]);
        float xx2 = fminf(ix2, jb2[b]);
        float yy2 = fminf(iy2, jb3[b]);
        float iw = fmaxf(xx2 - xx1, 0.f);
        float ih = fmaxf(yy2 - yy1, 0.f);
        float inter = iw * ih;
        float jarea = (jb2[b] - jb0[b]) * (jb3[b] - jb1[b]);
        float iou = inter / (iarea + jarea - inter);
        if (j > i && iou > 0.7f) word |= (1ull << b);
    }
    mask[(size_t)i * MW + jw] = word;
}

// ---------------------------------------------------------------- chunked single-wave greedy NMS
__global__ __launch_bounds__(64) void nms_scan_kernel(
    const ull* __restrict__ validbits,
    const ull* __restrict__ mask,
    const float* __restrict__ selbox, const float* __restrict__ selsc,
    float* __restrict__ out)
{
    __shared__ int kept[POSTK];
    const int l = threadIdx.x;
    ull supp0 = ~validbits[l];
    ull supp1 = (l < 30) ? ~validbits[64 + l] : ~0ull;
    int nk = 0;
    ull ownrow_next = mask[(size_t)l * MW + 0];
    for (int wi = 0; wi < 94 && nk < POSTK; ++wi) {
        ull ownrow = ownrow_next;
        if (wi < 93) ownrow_next = mask[(size_t)((wi + 1) * 64 + l) * MW + (wi + 1)];
        ull wsup = (wi < 64) ? __shfl(supp0, wi) : __shfl(supp1, wi - 64);
        ull active = ~wsup;
        if (!active) continue;
        ull keptbits = 0ull;
        while (active && nk < POSTK) {
            int b = __builtin_ctzll(active);
            keptbits |= (1ull << b);
            if (l == 0) kept[nk] = wi * 64 + b;
            nk++;
            ull rowb = __shfl(ownrow, b);
            ull gt = (b == 63) ? 0ull : (~0ull << (b + 1));
            active &= gt & ~rowb;
        }
        while (keptbits) {
            int b0 = __builtin_ctzll(keptbits); keptbits &= keptbits - 1;
            int b1 = -1, b2 = -1, b3 = -1;
            if (keptbits) { b1 = __builtin_ctzll(keptbits); keptbits &= keptbits - 1; }
            if (keptbits) { b2 = __builtin_ctzll(keptbits); keptbits &= keptbits - 1; }
            if (keptbits) { b3 = __builtin_ctzll(keptbits); keptbits &= keptbits - 1; }
            const ull* r0 = mask + (size_t)(wi * 64 + b0) * MW;
            ull t0a = r0[l], t0b = (l < 30) ? r0[64 + l] : 0ull;
            ull t1a = 0, t1b = 0, t2a = 0, t2b = 0, t3a = 0, t3b = 0;
            if (b1 >= 0) { const ull* r1 = mask + (size_t)(wi * 64 + b1) * MW; t1a = r1[l]; t1b = (l < 30) ? r1[64 + l] : 0ull; }
            if (b2 >= 0) { const ull* r2 = mask + (size_t)(wi * 64 + b2) * MW; t2a = r2[l]; t2b = (l < 30) ? r2[64 + l] : 0ull; }
            if (b3 >= 0) { const ull* r3 = mask + (size_t)(wi * 64 + b3) * MW; t3a = r3[l]; t3b = (l < 30) ? r3[64 + l] : 0ull; }
            supp0 |= t0a | t1a | t2a | t3a;
            supp1 |= t0b | t1b | t2b | t3b;
        }
    }
    __syncthreads();
    for (int r = l; r < POSTK; r += 64) {
        if (r < nk) {
            int i = kept[r];
            out[r * 5 + 0] = selbox[i * 4 + 0];
            out[r * 5 + 1] = selbox[i * 4 + 1];
            out[r * 5 + 2] = selbox[i * 4 + 2];
            out[r * 5 + 3] = selbox[i * 4 + 3];
            out[r * 5 + 4] = selsc[i];
        } else {
            out[r * 5 + 0] = 0.f; out[r * 5 + 1] = 0.f;
            out[r * 5 + 2] = 0.f; out[r * 5 + 3] = 0.f;
            out[r * 5 + 4] = 0.f;
        }
    }
}

// ---------------------------------------------------------------- launch
extern "C" void kernel_launch(void* const* d_in, const int* in_sizes, int n_in,
                              void* d_out, int out_size, void* d_ws, size_t ws_size,
                              hipStream_t stream) {
    const float* feat    = (const float*)d_in[1];
    const float* conv_w  = (const float*)d_in[2];
    const float* conv_b  = (const float*)d_in[3];
    const float* cls_w   = (const float*)d_in[4];
    const float* cls_b   = (const float*)d_in[5];
    const float* bbox_w  = (const float*)d_in[6];
    const float* bbox_b  = (const float*)d_in[7];
    float* out = (float*)d_out;

    char* ws = (char*)d_ws;
    float*    part      = (float*)(ws + 0);                 // 33,554,432 (2 halves)
    float*    wt        = (float*)(ws + 33554432);          //  2,359,296
    float*    bb        = (float*)(ws + 35913728);          //  2,359,296
    float*    scores    = (float*)(ws + 38273024);          //    589,824
    unsigned* hist1     = (unsigned*)(ws + 38862848);       //     65,536
    unsigned* meta      = (unsigned*)(ws + 39190528);       //        256
    ull*      cand      = (ull*)(ws + 39190784);            //     65,536
    ull*      sorted    = (ull*)(ws + 39256320);            //     65,536
    float*    selbox    = (float*)(ws + 39387392);          //     96,256
    float*    selsc     = (float*)(ws + 39483648);          //     24,064
    ull*      validbits = (ull*)(ws + 39507712);            //        768
    ull*      mask      = (ull*)(ws + 39508480);            //  4,608,000  -> total 44,116,480

    wt_kernel<<<2304, 256, 0, stream>>>(conv_w, wt, hist1, validbits);
    conv3x3_half_kernel<<<dim3(4, 16, 16), dim3(32, 8), 0, stream>>>(feat, wt, part);
    heads_kernel<<<256, 256, 0, stream>>>(part, conv_b, cls_w, cls_b, bbox_w, bbox_b, scores, bb);
    hist1_kernel<<<64, 1024, 0, stream>>>(scores, hist1);
    topk_finish_kernel<<<1, 1024, 0, stream>>>(scores, hist1, meta, cand);
    sortA_kernel<<<4, 1024, 0, stream>>>(cand, meta, sorted);
    merge_decode_kernel<<<32, 256, 0, stream>>>(sorted, bb, selbox, selsc, validbits);
    maskbuild_kernel<<<dim3(24, 94), 256, 0, stream>>>(selbox, mask);
    nms_scan_kernel<<<1, 64, 0, stream>>>(validbits, mask, selbox, selsc, out);
}